// Round 1
// baseline (138.065 us; speedup 1.0000x reference)
//
#include <hip/hip_runtime.h>

#define NT 300
#define NS 30
#define GRD 512
#define R2C 2500.0f    // == {d2 : sqrtf(d2) <= 50.0f}, exact (see analysis)
#define M2C 62500.0f   // == {d2 : sqrtf(d2) <= 250.0f}, exact

// d_ws layout: wM[NS*NT] floats, then c[NS] floats.

__global__ __launch_bounds__(320) void sensor_prep_kernel(
    const float* __restrict__ tx, const float* __restrict__ ty,
    const float* __restrict__ tw, const float* __restrict__ sx,
    const float* __restrict__ sy,
    float* __restrict__ wM, float* __restrict__ c)
{
    __shared__ float s_sx[NS], s_sy[NS];
    __shared__ float s_base[NS];
    __shared__ float s_cur;
    const int tid = threadIdx.x;
    if (tid < NS) { s_sx[tid] = sx[tid]; s_sy[tid] = sy[tid]; s_base[tid] = 0.0f; }
    if (tid == 0) s_cur = 0.0f;
    __syncthreads();
    if (tid < NT) {
        const float x = tx[tid], y = ty[tid], w = tw[tid];
        unsigned mask = 0;
        int cnt = 0;
        for (int s = 0; s < NS; ++s) {
            const float dx = s_sx[s] - x;
            const float dy = s_sy[s] - y;
            const float d2 = __fadd_rn(__fmul_rn(dx, dx), __fmul_rn(dy, dy));
            if (d2 <= R2C) { mask |= (1u << s); ++cnt; }
        }
        if (cnt > 0) atomicAdd(&s_cur, w);
        for (int s = 0; s < NS; ++s) {
            const int cov = (mask >> s) & 1;
            const int others = (cnt - cov) > 0;   // covered by some OTHER sensor
            wM[s * NT + tid] = others ? 0.0f : w;
            if (others) atomicAdd(&s_base[s], w);
        }
    }
    __syncthreads();
    if (tid < NS) c[tid] = s_base[tid] - s_cur;   // base[s] - current_reward
}

__global__ __launch_bounds__(256) void sensor_main_kernel(
    const float* __restrict__ tx, const float* __restrict__ ty,
    const float* __restrict__ sx, const float* __restrict__ sy,
    const float* __restrict__ wM, const float* __restrict__ c,
    float* __restrict__ out)
{
    __shared__ float2 s_txy[NT];
    __shared__ float  s_wM[NS * NT];
    __shared__ float  s_c[NS];
    __shared__ float2 s_sxy[NS];
    const int tid = threadIdx.x;
    for (int i = tid; i < NS * NT; i += 256) s_wM[i] = wM[i];
    for (int i = tid; i < NT; i += 256) s_txy[i] = make_float2(tx[i], ty[i]);
    if (tid < NS) { s_c[tid] = c[tid]; s_sxy[tid] = make_float2(sx[tid], sy[tid]); }
    __syncthreads();

    const int idx = blockIdx.x * 256 + tid;          // 0 .. 512*512-1
    const int gx = idx >> 9;
    const int gy = idx & (GRD - 1);
    const float gxf = (float)gx, gyf = (float)gy;

    float acc[NS];
#pragma unroll
    for (int s = 0; s < NS; ++s) acc[s] = 0.0f;

    for (int t = 0; t < NT; ++t) {
        const float2 p = s_txy[t];
        const float dx = gxf - p.x;
        const float dy = gyf - p.y;
        const float d2 = __fadd_rn(__fmul_rn(dx, dx), __fmul_rn(dy, dy));
        if (d2 <= R2C) {
#pragma unroll
            for (int s = 0; s < NS; ++s) acc[s] += s_wM[s * NT + t];
        }
    }

#pragma unroll
    for (int s = 0; s < NS; ++s) {
        const float2 sp = s_sxy[s];
        const float rx = sp.x - gxf;
        const float ry = sp.y - gyf;
        const float r2 = __fadd_rn(__fmul_rn(rx, rx), __fmul_rn(ry, ry));
        const float v = fmaxf(acc[s] + s_c[s], 0.0f);
        out[((size_t)s << 18) + (size_t)idx] = (r2 <= M2C) ? v : 0.0f;
    }
}

extern "C" void kernel_launch(void* const* d_in, const int* in_sizes, int n_in,
                              void* d_out, int out_size, void* d_ws, size_t ws_size,
                              hipStream_t stream) {
    const float* tx = (const float*)d_in[0];
    const float* ty = (const float*)d_in[1];
    const float* tw = (const float*)d_in[2];
    const float* sx = (const float*)d_in[3];
    const float* sy = (const float*)d_in[4];
    float* out = (float*)d_out;

    float* wM = (float*)d_ws;            // NS*NT floats
    float* c  = wM + NS * NT;            // NS floats

    sensor_prep_kernel<<<1, 320, 0, stream>>>(tx, ty, tw, sx, sy, wM, c);

    const int cells = GRD * GRD;         // 262144
    sensor_main_kernel<<<cells / 256, 256, 0, stream>>>(tx, ty, sx, sy, wM, c, out);
}

// Round 2
// 95.546 us; speedup vs baseline: 1.4450x; 1.4450x over previous
//
#include <hip/hip_runtime.h>

#define NT 300
#define NS 30
#define GRD 512
#define R2C 2500.0f    // {d2 : sqrtf(d2) <= 50.0f} == {d2 <= 2500.0f}, exact
#define M2C 62500.0f   // {d2 : sqrtf(d2) <= 250.0f} == {d2 <= 62500.0f}, exact

// d_ws layout:
//   float4 packed[NT]      -- (x, y, w, 0); segments: s=0..29 singles lists, seg 30 = cnt==0 list
//   int    offs[NS+2]      -- seg s occupies [offs[s], offs[s+1]); offs[31] = total entries
//   float  cvals[NS]       -- c[s] = -sum(w over singles of s) = base[s] - current_reward

__global__ __launch_bounds__(320) void sensor_prep_kernel(
    const float* __restrict__ tx, const float* __restrict__ ty,
    const float* __restrict__ tw, const float* __restrict__ sx,
    const float* __restrict__ sy,
    float4* __restrict__ packed, int* __restrict__ offs, float* __restrict__ cvals)
{
    __shared__ float s_sx[NS], s_sy[NS];
    __shared__ float s_sumw[NS];
    __shared__ int   s_cnt[NS + 1];
    __shared__ int   s_off[NS + 2];
    const int tid = threadIdx.x;
    if (tid < NS) { s_sx[tid] = sx[tid]; s_sy[tid] = sy[tid]; s_sumw[tid] = 0.0f; }
    if (tid < NS + 1) s_cnt[tid] = 0;
    __syncthreads();

    int cls = -1, pos = 0;
    float x = 0.0f, y = 0.0f, w = 0.0f;
    if (tid < NT) {
        x = tx[tid]; y = ty[tid]; w = tw[tid];
        int cnt = 0, sstar = 0;
        for (int s = 0; s < NS; ++s) {
            const float dx = s_sx[s] - x;
            const float dy = s_sy[s] - y;
            const float d2 = __fadd_rn(__fmul_rn(dx, dx), __fmul_rn(dy, dy));
            if (d2 <= R2C) { ++cnt; sstar = s; }
        }
        if (cnt == 0) cls = NS;                                  // A-list
        else if (cnt == 1) { cls = sstar; atomicAdd(&s_sumw[sstar], w); }
        // cnt >= 2: contributes to no sensor's gain -> dropped
        if (cls >= 0) pos = atomicAdd(&s_cnt[cls], 1);
    }
    __syncthreads();
    if (tid == 0) {
        int acc = 0;
        for (int L = 0; L <= NS; ++L) { s_off[L] = acc; acc += s_cnt[L]; }
        s_off[NS + 1] = acc;
    }
    __syncthreads();
    if (cls >= 0) packed[s_off[cls] + pos] = make_float4(x, y, w, 0.0f);
    if (tid < NS + 2) offs[tid] = s_off[tid];
    if (tid < NS) cvals[tid] = -s_sumw[tid];
}

__global__ __launch_bounds__(256) void sensor_main_kernel(
    const float* __restrict__ sx, const float* __restrict__ sy,
    const float4* __restrict__ packed, const int* __restrict__ offs,
    const float* __restrict__ cvals, float* __restrict__ out)
{
    __shared__ float4 s_pk[NT];
    __shared__ int    s_off[NS + 2];
    __shared__ float  s_c[NS];
    __shared__ float  s_sx[NS], s_sy[NS];
    const int tid = threadIdx.x;
    if (tid < NS + 2) s_off[tid] = offs[tid];
    if (tid < NS) { s_c[tid] = cvals[tid]; s_sx[tid] = sx[tid]; s_sy[tid] = sy[tid]; }
    __syncthreads();
    const int total = s_off[NS + 1];
    for (int i = tid; i < total; i += 256) s_pk[i] = packed[i];
    __syncthreads();

    const float gxf  = (float)blockIdx.x;          // one gx column per block
    const int   gy0  = 2 * tid;
    const float gy0f = (float)gy0;
    const float gy1f = (float)(gy0 + 1);

    // A: gain from currently-uncovered targets (same for every sensor)
    float A0 = 0.0f, A1 = 0.0f;
    for (int j = s_off[NS]; j < total; ++j) {
        const float4 e = s_pk[j];
        const float dx  = gxf - e.x;
        const float dxx = __fmul_rn(dx, dx);
        if (dxx <= R2C) {                          // exact conservative skip (fadd is monotone)
            const float dy0 = gy0f - e.y;
            const float dy1 = gy1f - e.y;
            if (__fadd_rn(dxx, __fmul_rn(dy0, dy0)) <= R2C) A0 += e.z;
            if (__fadd_rn(dxx, __fmul_rn(dy1, dy1)) <= R2C) A1 += e.z;
        }
    }

    const size_t obase = ((size_t)blockIdx.x << 9) + (size_t)gy0;
    for (int s = 0; s < NS; ++s) {
        float v0 = A0 + s_c[s];                    // exact integers, order-free
        float v1 = A1 + s_c[s];
        const int je = s_off[s + 1];
        for (int j = s_off[s]; j < je; ++j) {      // singles of sensor s still in range
            const float4 e = s_pk[j];
            const float dx  = gxf - e.x;
            const float dxx = __fmul_rn(dx, dx);
            if (dxx <= R2C) {
                const float dy0 = gy0f - e.y;
                const float dy1 = gy1f - e.y;
                if (__fadd_rn(dxx, __fmul_rn(dy0, dy0)) <= R2C) v0 += e.z;
                if (__fadd_rn(dxx, __fmul_rn(dy1, dy1)) <= R2C) v1 += e.z;
            }
        }
        const float rx  = s_sx[s] - gxf;
        const float ry0 = s_sy[s] - gy0f;
        const float ry1 = s_sy[s] - gy1f;
        const float rxx = __fmul_rn(rx, rx);
        const float o0 = (__fadd_rn(rxx, __fmul_rn(ry0, ry0)) <= M2C) ? fmaxf(v0, 0.0f) : 0.0f;
        const float o1 = (__fadd_rn(rxx, __fmul_rn(ry1, ry1)) <= M2C) ? fmaxf(v1, 0.0f) : 0.0f;
        *reinterpret_cast<float2*>(out + (((size_t)s << 18) + obase)) = make_float2(o0, o1);
    }
}

extern "C" void kernel_launch(void* const* d_in, const int* in_sizes, int n_in,
                              void* d_out, int out_size, void* d_ws, size_t ws_size,
                              hipStream_t stream) {
    const float* tx = (const float*)d_in[0];
    const float* ty = (const float*)d_in[1];
    const float* tw = (const float*)d_in[2];
    const float* sx = (const float*)d_in[3];
    const float* sy = (const float*)d_in[4];
    float* out = (float*)d_out;

    float4* packed = (float4*)d_ws;
    int*    offs   = (int*)(packed + NT);
    float*  cvals  = (float*)(offs + NS + 2);

    sensor_prep_kernel<<<1, 320, 0, stream>>>(tx, ty, tw, sx, sy, packed, offs, cvals);
    sensor_main_kernel<<<GRD, 256, 0, stream>>>(sx, sy, packed, offs, cvals, out);
}

// Round 3
// 92.230 us; speedup vs baseline: 1.4970x; 1.0360x over previous
//
#include <hip/hip_runtime.h>

#define NT 300
#define NS 30
#define GRD 512
#define R2C 2500.0f    // {d2 : sqrtf(d2) <= 50.0f} == {d2 <= 2500.0f}, exact
#define M2C 62500.0f   // {d2 : sqrtf(d2) <= 250.0f} == {d2 <= 62500.0f}, exact

// Single fused kernel: each block (one gx column) redundantly classifies the
// 300 targets (9k flops — trivial) into per-sensor "singles" lists + the
// "uncovered" list, entirely in LDS, then sweeps its 512 gy cells.
// Targets covered by >=2 sensors contribute to no sensor's gain and are dropped.
// c[s] = base[s] - current_reward = -sum(w over singles of s): exact small
// integers in f32, so summation order is irrelevant. All coverage/reach
// predicates use the bit-exact squared-distance form (no FMA contraction).

__global__ __launch_bounds__(256) void sensor_fused_kernel(
    const float* __restrict__ tx, const float* __restrict__ ty,
    const float* __restrict__ tw, const float* __restrict__ sx,
    const float* __restrict__ sy, float* __restrict__ out)
{
    __shared__ float  s_sx[NS], s_sy[NS];
    __shared__ float  s_sumw[NS];
    __shared__ int    s_cnt[NS + 1];
    __shared__ int    s_off[NS + 2];
    __shared__ float4 s_pk[NT];
    __shared__ float  s_c[NS];
    const int tid = threadIdx.x;

    // ---- Phase A: per-block redundant prep (all in LDS) ----
    if (tid < NS) { s_sx[tid] = sx[tid]; s_sy[tid] = sy[tid]; s_sumw[tid] = 0.0f; }
    if (tid < NS + 1) s_cnt[tid] = 0;
    __syncthreads();

    int   cls[2] = { -1, -1 };
    int   pos[2] = { 0, 0 };
    float X[2], Y[2], W[2];
#pragma unroll
    for (int k = 0; k < 2; ++k) {
        const int t = tid + k * 256;
        if (t < NT) {
            const float x = tx[t], y = ty[t], w = tw[t];
            int cnt = 0, sstar = 0;
            for (int s = 0; s < NS; ++s) {
                const float dx = s_sx[s] - x;
                const float dy = s_sy[s] - y;
                const float d2 = __fadd_rn(__fmul_rn(dx, dx), __fmul_rn(dy, dy));
                if (d2 <= R2C) { ++cnt; sstar = s; }
            }
            int c = -1;
            if (cnt == 0) c = NS;                                   // uncovered list
            else if (cnt == 1) { c = sstar; atomicAdd(&s_sumw[sstar], w); }
            if (c >= 0) pos[k] = atomicAdd(&s_cnt[c], 1);
            cls[k] = c; X[k] = x; Y[k] = y; W[k] = w;
        }
    }
    __syncthreads();
    if (tid == 0) {
        int acc = 0;
        for (int L = 0; L <= NS; ++L) { s_off[L] = acc; acc += s_cnt[L]; }
        s_off[NS + 1] = acc;
    }
    __syncthreads();
#pragma unroll
    for (int k = 0; k < 2; ++k)
        if (cls[k] >= 0) s_pk[s_off[cls[k]] + pos[k]] = make_float4(X[k], Y[k], W[k], 0.0f);
    if (tid < NS) s_c[tid] = -s_sumw[tid];
    __syncthreads();

    // ---- Phase B: sweep this block's gx column, 2 gy cells per thread ----
    const int total = s_off[NS + 1];
    const float gxf  = (float)blockIdx.x;
    const int   gy0  = 2 * tid;
    const float gy0f = (float)gy0;
    const float gy1f = (float)(gy0 + 1);

    // A: gain from currently-uncovered targets (same for every sensor)
    float A0 = 0.0f, A1 = 0.0f;
    for (int j = s_off[NS]; j < total; ++j) {
        const float4 e = s_pk[j];
        const float dx  = gxf - e.x;
        const float dxx = __fmul_rn(dx, dx);
        if (dxx <= R2C) {                          // exact conservative skip (fadd monotone)
            const float dy0 = gy0f - e.y;
            const float dy1 = gy1f - e.y;
            if (__fadd_rn(dxx, __fmul_rn(dy0, dy0)) <= R2C) A0 += e.z;
            if (__fadd_rn(dxx, __fmul_rn(dy1, dy1)) <= R2C) A1 += e.z;
        }
    }

    const size_t obase = ((size_t)blockIdx.x << 9) + (size_t)gy0;
    for (int s = 0; s < NS; ++s) {
        float v0 = A0 + s_c[s];                    // exact integers, order-free
        float v1 = A1 + s_c[s];
        const int je = s_off[s + 1];
        for (int j = s_off[s]; j < je; ++j) {      // singles of sensor s still in range
            const float4 e = s_pk[j];
            const float dx  = gxf - e.x;
            const float dxx = __fmul_rn(dx, dx);
            if (dxx <= R2C) {
                const float dy0 = gy0f - e.y;
                const float dy1 = gy1f - e.y;
                if (__fadd_rn(dxx, __fmul_rn(dy0, dy0)) <= R2C) v0 += e.z;
                if (__fadd_rn(dxx, __fmul_rn(dy1, dy1)) <= R2C) v1 += e.z;
            }
        }
        const float rx  = s_sx[s] - gxf;
        const float ry0 = s_sy[s] - gy0f;
        const float ry1 = s_sy[s] - gy1f;
        const float rxx = __fmul_rn(rx, rx);
        const float o0 = (__fadd_rn(rxx, __fmul_rn(ry0, ry0)) <= M2C) ? fmaxf(v0, 0.0f) : 0.0f;
        const float o1 = (__fadd_rn(rxx, __fmul_rn(ry1, ry1)) <= M2C) ? fmaxf(v1, 0.0f) : 0.0f;
        *reinterpret_cast<float2*>(out + (((size_t)s << 18) + obase)) = make_float2(o0, o1);
    }
}

extern "C" void kernel_launch(void* const* d_in, const int* in_sizes, int n_in,
                              void* d_out, int out_size, void* d_ws, size_t ws_size,
                              hipStream_t stream) {
    const float* tx = (const float*)d_in[0];
    const float* ty = (const float*)d_in[1];
    const float* tw = (const float*)d_in[2];
    const float* sx = (const float*)d_in[3];
    const float* sy = (const float*)d_in[4];
    float* out = (float*)d_out;
    (void)d_ws; (void)ws_size;

    sensor_fused_kernel<<<GRD, 256, 0, stream>>>(tx, ty, tw, sx, sy, out);
}